// Round 1
// baseline (477.697 us; speedup 1.0000x reference)
//
#include <hip/hip_runtime.h>
#include <math.h>

// Problem constants
#define B_   16
#define C_   64
#define H_   256
#define W_   256
#define CKK_ 576      // 64*3*3
#define FC_  512
#define ROWS 16       // output rows per wave in the conv kernel

typedef float f32x4 __attribute__((ext_vector_type(4)));

// ---------------------------------------------------------------------------
// Kernel A: layer1  h = relu(F_c @ W1 + b1)   (unchanged, verified)
// ---------------------------------------------------------------------------
__global__ __launch_bounds__(256) void mlp_layer1_kernel(
    const float* __restrict__ F_c,   // [B,512]
    const float* __restrict__ W1,    // [512,576]
    const float* __restrict__ b1,    // [576]
    float* __restrict__ h_out)       // [B,576] (in ws)
{
    const int b  = blockIdx.x / 9;
    const int jg = blockIdx.x % 9;
    const int jl = threadIdx.x & 63;
    const int p  = threadIdx.x >> 6;      // 0..3, K-chunk
    const int j  = jg * 64 + jl;

    __shared__ float xs[FC_];
    __shared__ float partial[256];

    xs[threadIdx.x]       = F_c[b * FC_ + threadIdx.x];
    xs[threadIdx.x + 256] = F_c[b * FC_ + threadIdx.x + 256];
    __syncthreads();

    const int i0 = p * 128;
    const float* wp = W1 + (size_t)i0 * CKK_ + j;
    float acc = 0.0f;
    #pragma unroll 8
    for (int i = 0; i < 128; ++i)
        acc = fmaf(xs[i0 + i], wp[(size_t)i * CKK_], acc);
    partial[threadIdx.x] = acc;
    __syncthreads();

    if (threadIdx.x < 64) {
        float s = partial[jl] + partial[64 + jl] + partial[128 + jl] + partial[192 + jl];
        h_out[b * CKK_ + j] = fmaxf(s + b1[j], 0.0f);
    }
}

// ---------------------------------------------------------------------------
// Kernel B: layer2 logits = h @ W2 + b2   (unchanged, verified)
// ---------------------------------------------------------------------------
__global__ __launch_bounds__(256) void mlp_layer2_kernel(
    const float* __restrict__ h,     // [B,576] (ws)
    const float* __restrict__ W2,    // [576,576]
    const float* __restrict__ b2,    // [576]
    float* __restrict__ logits)      // [B,576] (ws)
{
    const int b  = blockIdx.x / 9;
    const int jg = blockIdx.x % 9;
    const int jl = threadIdx.x & 63;
    const int p  = threadIdx.x >> 6;
    const int j  = jg * 64 + jl;

    __shared__ float xs[CKK_];
    __shared__ float partial[256];

    xs[threadIdx.x]       = h[b * CKK_ + threadIdx.x];
    xs[threadIdx.x + 256] = h[b * CKK_ + threadIdx.x + 256];
    if (threadIdx.x < CKK_ - 512)
        xs[threadIdx.x + 512] = h[b * CKK_ + threadIdx.x + 512];
    __syncthreads();

    const int i0 = p * 144;
    const float* wp = W2 + (size_t)i0 * CKK_ + j;
    float acc = 0.0f;
    #pragma unroll 8
    for (int i = 0; i < 144; ++i)
        acc = fmaf(xs[i0 + i], wp[(size_t)i * CKK_], acc);
    partial[threadIdx.x] = acc;
    __syncthreads();

    if (threadIdx.x < 64) {
        float s = partial[jl] + partial[64 + jl] + partial[128 + jl] + partial[192 + jl];
        logits[b * CKK_ + j] = s + b2[j];
    }
}

// ---------------------------------------------------------------------------
// Kernel C: softmax over 576 logits per sample. (unchanged, verified)
// ---------------------------------------------------------------------------
__global__ __launch_bounds__(CKK_) void softmax_kernel(
    const float* __restrict__ logits,  // [B,576] (ws)
    float* __restrict__ kw_out)        // [B,576] (d_out tail)
{
    const int b    = blockIdx.x;
    const int j    = threadIdx.x;
    const int lane = j & 63;
    const int wave = j >> 6;

    __shared__ float red[12];

    const float lg = logits[b * CKK_ + j];

    float m = lg;
    #pragma unroll
    for (int off = 32; off > 0; off >>= 1)
        m = fmaxf(m, __shfl_xor(m, off));
    if (lane == 0) red[wave] = m;
    __syncthreads();
    if (j == 0) {
        float mm = red[0];
        for (int i = 1; i < 9; ++i) mm = fmaxf(mm, red[i]);
        red[9] = mm;
    }
    __syncthreads();
    const float mm = red[9];

    const float e = expf(lg - mm);
    float s = e;
    #pragma unroll
    for (int off = 32; off > 0; off >>= 1)
        s += __shfl_xor(s, off);
    if (lane == 0) red[wave] = s;
    __syncthreads();
    if (j == 0) {
        float ss = 0.0f;
        for (int i = 0; i < 9; ++i) ss += red[i];
        red[10] = ss;
    }
    __syncthreads();

    kw_out[b * CKK_ + j] = e / red[10];
}

// ---------------------------------------------------------------------------
// Kernel D: depthwise 3x3 conv with reflect padding.
// One wave = 16 output rows x 256 cols. Raw float4 row loads are software-
// pipelined one iteration ahead of their shuffle+use, so the vmcnt wait for
// row r+1 sits behind a full row of FMAs. Output stored nontemporally (never
// re-read) to keep L2 for halo-row reuse.
// ---------------------------------------------------------------------------
__device__ __forceinline__ void shuffle_row(const float4 c, int lane, float v[6])
{
    const float left  = __shfl_up(c.w, 1);    // row[x0-1] from lane-1
    const float right = __shfl_down(c.x, 1);  // row[x0+4] from lane+1
    v[0] = (lane == 0)  ? c.y : left;         // reflect col -1  -> col 1
    v[5] = (lane == 63) ? c.z : right;        // reflect col 256 -> col 254
    v[1] = c.x; v[2] = c.y; v[3] = c.z; v[4] = c.w;
}

__global__ __launch_bounds__(256) void dwconv_kernel(
    const float* __restrict__ in,    // [B*C,256,256]
    const float* __restrict__ kw,    // [B*C,9]
    float* __restrict__ out)         // [B*C,256,256]
{
    const int tid  = threadIdx.x;
    const int lane = tid & 63;
    const int wave = tid >> 6;

    const int tilesPerBC = H_ / (ROWS * 4);          // 4
    const int bc   = blockIdx.x / tilesPerBC;
    const int tile = blockIdx.x % tilesPerBC;
    const int y0   = tile * (ROWS * 4) + wave * ROWS;
    const int x0   = lane * 4;

    const float* base  = in  + (size_t)bc * H_ * W_;
    float*       obase = out + (size_t)bc * H_ * W_;

    const float* w = kw + bc * 9;
    const float w0 = w[0], w1 = w[1], w2 = w[2];
    const float w3 = w[3], w4 = w[4], w5 = w[5];
    const float w6 = w[6], w7 = w[7], w8 = w[8];

    float a[6], bb[6], c[6];
    const int ym = (y0 == 0) ? 1 : y0 - 1;           // reflect row -1 -> 1
    // prologue: raw loads for rows ym, y0, y0+1 (y0+1 <= 241 < H_ always)
    float4 ra = *(const float4*)(base + (size_t)ym * W_ + x0);
    float4 rb = *(const float4*)(base + (size_t)y0 * W_ + x0);
    float4 rc = *(const float4*)(base + (size_t)(y0 + 1) * W_ + x0);
    shuffle_row(ra, lane, a);
    shuffle_row(rb, lane, bb);

    #pragma unroll
    for (int r = 0; r < ROWS; ++r) {
        // prefetch RAW row y0+r+2 (used next iteration); reflect/clamp keeps
        // the address in-bounds even for the final (unused) prefetch
        int ynn = y0 + r + 2;
        if (ynn >= H_) ynn = 2 * H_ - 2 - ynn;       // 256->254 (257->253 unused)
        const float4 rn = *(const float4*)(base + (size_t)ynn * W_ + x0);

        shuffle_row(rc, lane, c);

        float4 o;
        o.x = fmaf(a[0], w0, fmaf(a[1], w1, fmaf(a[2], w2,
              fmaf(bb[0], w3, fmaf(bb[1], w4, fmaf(bb[2], w5,
              fmaf(c[0], w6, fmaf(c[1], w7, c[2] * w8))))))));
        o.y = fmaf(a[1], w0, fmaf(a[2], w1, fmaf(a[3], w2,
              fmaf(bb[1], w3, fmaf(bb[2], w4, fmaf(bb[3], w5,
              fmaf(c[1], w6, fmaf(c[2], w7, c[3] * w8))))))));
        o.z = fmaf(a[2], w0, fmaf(a[3], w1, fmaf(a[4], w2,
              fmaf(bb[2], w3, fmaf(bb[3], w4, fmaf(bb[4], w5,
              fmaf(c[2], w6, fmaf(c[3], w7, c[4] * w8))))))));
        o.w = fmaf(a[3], w0, fmaf(a[4], w1, fmaf(a[5], w2,
              fmaf(bb[3], w3, fmaf(bb[4], w4, fmaf(bb[5], w5,
              fmaf(c[3], w6, fmaf(c[4], w7, c[5] * w8))))))));

        f32x4 ov; ov.x = o.x; ov.y = o.y; ov.z = o.z; ov.w = o.w;
        __builtin_nontemporal_store(ov, (f32x4*)(obase + (size_t)(y0 + r) * W_ + x0));

        #pragma unroll
        for (int i = 0; i < 6; ++i) { a[i] = bb[i]; bb[i] = c[i]; }
        rc = rn;
    }
}

// ---------------------------------------------------------------------------
extern "C" void kernel_launch(void* const* d_in, const int* in_sizes, int n_in,
                              void* d_out, int out_size, void* d_ws, size_t ws_size,
                              hipStream_t stream)
{
    const float* F_d = (const float*)d_in[0];
    const float* F_c = (const float*)d_in[1];
    const float* W1  = (const float*)d_in[2];
    const float* b1  = (const float*)d_in[3];
    const float* W2  = (const float*)d_in[4];
    const float* b2  = (const float*)d_in[5];

    float* out    = (float*)d_out;
    float* kw     = out + (size_t)B_ * C_ * H_ * W_;  // kernel_weights output slot
    float* h_ws   = (float*)d_ws;                     // [B,576]
    float* lg_ws  = h_ws + B_ * CKK_;                 // [B,576]

    mlp_layer1_kernel<<<B_ * 9, 256, 0, stream>>>(F_c, W1, b1, h_ws);
    mlp_layer2_kernel<<<B_ * 9, 256, 0, stream>>>(h_ws, W2, b2, lg_ws);
    softmax_kernel<<<B_, CKK_, 0, stream>>>(lg_ws, kw);

    const int tilesPerBC = H_ / (ROWS * 4);           // 4
    dwconv_kernel<<<B_ * C_ * tilesPerBC, 256, 0, stream>>>(F_d, kw, out);
}